// Round 19
// baseline (107.479 us; speedup 1.0000x reference)
//
#include <hip/hip_runtime.h>
#include <math.h>

constexpr int B_ = 8192;
constexpr int T_ = 512;
constexpr int CH = 16;                     // steps per chunk
constexpr int NCH = T_ / CH;               // 32 chunks

__device__ __forceinline__ float sp_(float x) {
    return fmaxf(x, 0.0f) + log1pf(expf(-fabsf(x)));  // stable softplus
}
__device__ __forceinline__ float sg_(float x) { return 1.0f / (1.0f + expf(-x)); }
__device__ __forceinline__ float clipf(float x, float lo, float hi) { return fminf(fmaxf(x, lo), hi); }
__device__ __forceinline__ float sel(bool c, float a, float b) { return c ? a : b; }

// ONE kernel: raw input -> codes (LDS) -> affine maps + wave-scan -> logits -> staged flush.
// R18 structure with staging split into 4 quarters (16.9 KB LDS) -> 8 blocks/CU.
__global__ __launch_bounds__(256, 8) void castro_one(const float* __restrict__ in,
                                                     const float* __restrict__ p,
                                                     float* __restrict__ out) {
    __shared__ char smem[8 * 4 * 33 * 16];   // 16896 B: codes (8KB) unioned with staging
    uint4* cc4 = reinterpret_cast<uint4*>(smem);          // [256]
    uint4* rr4 = reinterpret_cast<uint4*>(smem) + 256;    // [256]
    unsigned char* ccb = reinterpret_cast<unsigned char*>(cc4);
    unsigned char* rrb = reinterpret_cast<unsigned char*>(rr4);
    float4* stg = reinterpret_cast<float4*>(smem);        // [sess][tl][k(+1)] = [8][4][33]

    const int tid = threadIdx.x;
    const int b0  = blockIdx.x * 8;          // first session of this block

    // ---- phase 1: coalesced read of 8 sessions, bit-extract to LDS ----
    const float4* __restrict__ in4 = reinterpret_cast<const float4*>(in) + (size_t)b0 * 1024;
#pragma unroll
    for (int it = 0; it < 32; ++it) {
        const int idx  = it * 256 + tid;      // 0..8191, lane-contiguous
        const float4 fv = in4[idx];
        const int sess = idx >> 10;           // session within block
        const int step = (idx & 1023) >> 1;   // 2 float4 per step
        if ((idx & 1) == 0) {
            ccb[sess * 512 + step] =
                (unsigned char)(fv.y > 0.5f ? 1 : (fv.z > 0.5f ? 2 : (fv.w > 0.5f ? 3 : 0)));
        } else {
            rrb[sess * 512 + step] = (fv.x > 0.5f) ? 4 : 0;   // rewards broadcast: .x suffices
        }
    }
    __syncthreads();

    // ---- phase 2: per-(sess,chunk) map + width-32 shuffle scan (verbatim) ----
    const int w    = tid >> 6;
    const int lane = tid & 63;
    const int k    = lane & 31;                  // chunk index
    const int sess = w * 2 + (lane >> 5);        // session within block
    const int b    = b0 + sess;

    const float beta_r = clipf(sp_(p[0]), 0.01f, 20.0f);
    const float lapse  = clipf(sg_(p[1]), 0.01f, 0.99f);
    const float prior  = clipf(sp_(p[2]), 0.01f, 0.99f);
    const float alpha  = clipf(sg_(p[3]), 0.01f, 0.99f);
    const float decay  = clipf(sg_(p[4]), 0.01f, 0.99f);
    const float ab1    = p[5];
    const float ab2    = p[6];
    const float pers   = sp_(p[7]);
    const float sw     = p[8];
    const float gamma  = sp_(p[10]);
    const float temp   = clipf(sp_(p[11]) + 1e-6f, 1e-6f, 100.0f);
    const float beta_p = sp_(p[12]);
    const float brt = beta_r / temp;
    const float l4  = lapse * 0.25f;
    const float oml = 1.0f - lapse;

    const float e0k = alpha * __powf(1.0f - 1e-3f, (float)(CH * k));

    uint4 cw;
    {
        const uint4 c4 = cc4[sess * 32 + k];
        const uint4 r4 = rr4[sess * 32 + k];
        cw.x = c4.x | r4.x; cw.y = c4.y | r4.y; cw.z = c4.z | r4.z; cw.w = c4.w | r4.w;
    }
    __syncthreads();   // codes LDS dead; staging may overwrite

    float m[4][4], v[4], n[4];
#pragma unroll
    for (int i = 0; i < 4; ++i) {
#pragma unroll
        for (int j = 0; j < 4; ++j) m[i][j] = (i == j) ? 1.0f : 0.0f;
        v[i] = 0.0f; n[i] = 0.0f;
    }
    int prev = -1, run = 0;
    float e = e0k;

#pragma unroll
    for (int ti = 0; ti < CH; ++ti) {
        const unsigned word = (ti < 4) ? cw.x : (ti < 8) ? cw.y : (ti < 12) ? cw.z : cw.w;
        const unsigned byte = (word >> (8 * (ti & 3))) & 0xffu;
        const int  cc = (int)(byte & 3u);
        const bool rf = (byte & 4u) != 0u;
        const float tgt = rf ? 1.0f : -gamma;
        e *= (1.0f - 1e-3f);
        run = (cc == prev) ? (run + 1) : 1;
        prev = cc;
#pragma unroll
        for (int i = 0; i < 4; ++i) {
            const bool hit = (i == cc);
            v[i] = hit ? tgt : v[i];
            n[i] += hit ? 1.0f : 0.0f;
#pragma unroll
            for (int j = 0; j < 4; ++j) m[i][j] = hit ? 0.0f : m[i][j];
        }
        const float aa = decay * (1.0f - e);
        const float bf = decay * e * 0.25f;
        float csum[4];
#pragma unroll
        for (int j = 0; j < 4; ++j) csum[j] = bf * ((m[0][j] + m[1][j]) + (m[2][j] + m[3][j]));
        const float vs = bf * ((v[0] + v[1]) + (v[2] + v[3]));
#pragma unroll
        for (int i = 0; i < 4; ++i) {
#pragma unroll
            for (int j = 0; j < 4; ++j) m[i][j] = fmaf(aa, m[i][j], csum[j]);
            v[i] = fmaf(aa, v[i], vs);
        }
    }

    // inclusive shuffle-scan of (M,v) over k
    float sm[4][4], sv[4];
#pragma unroll
    for (int i = 0; i < 4; ++i) {
#pragma unroll
        for (int j = 0; j < 4; ++j) sm[i][j] = m[i][j];
        sv[i] = v[i];
    }
#pragma unroll
    for (int d = 1; d < 32; d <<= 1) {
        float pm[4][4], pv[4];
#pragma unroll
        for (int i = 0; i < 4; ++i) {
#pragma unroll
            for (int j = 0; j < 4; ++j) pm[i][j] = __shfl_up(sm[i][j], d, 32);
            pv[i] = __shfl_up(sv[i], d, 32);
        }
        if (k >= d) {
            float nm[4][4], nv[4];
#pragma unroll
            for (int i = 0; i < 4; ++i) {
#pragma unroll
                for (int j = 0; j < 4; ++j)
                    nm[i][j] = fmaf(sm[i][0], pm[0][j], fmaf(sm[i][1], pm[1][j],
                               fmaf(sm[i][2], pm[2][j], sm[i][3] * pm[3][j])));
                nv[i] = fmaf(sm[i][0], pv[0], fmaf(sm[i][1], pv[1],
                        fmaf(sm[i][2], pv[2], fmaf(sm[i][3], pv[3], sv[i]))));
            }
#pragma unroll
            for (int i = 0; i < 4; ++i) {
#pragma unroll
                for (int j = 0; j < 4; ++j) sm[i][j] = nm[i][j];
                sv[i] = nv[i];
            }
        }
    }

    // exclusive map -> starting q for chunk k
    float q[4];
#pragma unroll
    for (int i = 0; i < 4; ++i) {
        float er0 = __shfl_up(sm[i][0], 1, 32);
        float er1 = __shfl_up(sm[i][1], 1, 32);
        float er2 = __shfl_up(sm[i][2], 1, 32);
        float er3 = __shfl_up(sm[i][3], 1, 32);
        float ev  = __shfl_up(sv[i], 1, 32);
        if (k == 0) { er0 = (i == 0); er1 = (i == 1); er2 = (i == 2); er3 = (i == 3); ev = 0.0f; }
        q[i] = fmaf(prior, ((er0 + er1) + (er2 + er3)), ev);
    }

    // cum counts: exclusive prefix sum (bit-exact)
    float cex[4];
#pragma unroll
    for (int i = 0; i < 4; ++i) {
        float s = n[i];
#pragma unroll
        for (int d = 1; d < 32; d <<= 1) {
            const float t = __shfl_up(s, d, 32);
            if (k >= d) s += t;
        }
        cex[i] = s - n[i];
    }

    // tsls via trailing-run scan (bit-exact)
    const float lcf  = (float)prev;
    const float runf = (float)run;
    float lcm1 = __shfl_up(lcf, 1, 32);
    if (k == 0) lcm1 = -1.0f;
    const bool u = (runf == 16.0f) && (lcf == lcm1);
    const unsigned long long bal = __ballot(u);
    const unsigned gm = (unsigned)(bal >> (lane & 32));
    const unsigned vsh = (k == 31) ? gm : (gm << (31 - k));
    const int c = __clz(~vsh);
    const float runsrc = __shfl(runf, (lane & 32) + (k - c));
    const float TR = 16.0f * (float)c + runsrc;
    float TRm1 = __shfl_up(TR, 1, 32);
    const float tslsS = (k == 0) ? 0.0f : (TRm1 - 1.0f);
    const float lcprev = (k == 0) ? -1.0f : lcm1;

    // ---- phase 3: logits staged through LDS in FOUR quarters ----
    float q0 = q[0], q1 = q[1], q2 = q[2], q3 = q[3];
    float c0 = cex[0], c1 = cex[1], c2 = cex[2], c3 = cex[3];
    float tsls = tslsS;
    float expl = e0k;
    int oldc = (int)lcprev;

    float4* __restrict__ out4 = reinterpret_cast<float4*>(out);

#pragma unroll
    for (int h = 0; h < 4; ++h) {
#pragma unroll
        for (int tl = 0; tl < 4; ++tl) {
            const int ti = h * 4 + tl;
            const unsigned word = (ti < 4) ? cw.x : (ti < 8) ? cw.y : (ti < 12) ? cw.z : cw.w;
            const unsigned byte = (word >> (8 * (ti & 3))) & 0xffu;
            const int  cc = (int)(byte & 3u);
            const bool rf = (byte & 4u) != 0u;
            const float target = sel(rf, 1.0f, -gamma);
            const int prv = oldc;
            const bool same = (cc == oldc);
            tsls = sel(same, tsls + 1.0f, 0.0f);
            expl *= (1.0f - 1e-3f);
            const bool i0 = (cc == 0), i1 = (cc == 1), i2 = (cc == 2), i3 = (cc == 3);
            q0 = sel(i0, target, q0);  c0 += sel(i0, 1.0f, 0.0f);
            q1 = sel(i1, target, q1);  c1 += sel(i1, 1.0f, 0.0f);
            q2 = sel(i2, target, q2);  c2 += sel(i2, 1.0f, 0.0f);
            q3 = sel(i3, target, q3);  c3 += sel(i3, 1.0f, 0.0f);
            const float qm  = 0.25f * ((q0 + q1) + (q2 + q3));
            const float omd = (1.0f - expl) * decay;
            const float eqd = (expl * decay) * qm;
            q0 = fmaf(omd, q0, eqd);
            q1 = fmaf(omd, q1, eqd);
            q2 = fmaf(omd, q2, eqd);
            q3 = fmaf(omd, q3, eqd);
            oldc = cc;

            const float s0 = fmaf(brt, q0, beta_p * __logf(1.0f + c0));
            const float s1 = fmaf(brt, q1, beta_p * __logf(1.0f + c1));
            const float s2 = fmaf(brt, q2, beta_p * __logf(1.0f + c2));
            const float s3 = fmaf(brt, q3, beta_p * __logf(1.0f + c3));
            const float mx = fmaxf(fmaxf(s0, s1), fmaxf(s2, s3));
            const float e0 = __expf(s0 - mx);
            const float e1 = __expf(s1 - mx);
            const float e2 = __expf(s2 - mx);
            const float e3 = __expf(s3 - mx);
            const float iz = oml / ((e0 + e1) + (e2 + e3));

            float l0 = __logf(fmaf(e0, iz, l4));
            float l1 = __logf(fmaf(e1, iz, l4));
            float l2 = __logf(fmaf(e2, iz, l4));
            float l3 = __logf(fmaf(e3, iz, l4));

            const float bcc = sel(same, pers, sw) + __logf(tsls + 1.0f);
            const int cc2 = cc ^ 2;
            l0 += sel(i0, bcc, 0.0f) + sel(prv == 0, ab1, 0.0f) + sel(cc2 == 0, ab2, 0.0f);
            l1 += sel(i1, bcc, 0.0f) + sel(prv == 1, ab1, 0.0f) + sel(cc2 == 1, ab2, 0.0f);
            l2 += sel(i2, bcc, 0.0f) + sel(prv == 2, ab1, 0.0f) + sel(cc2 == 2, ab2, 0.0f);
            l3 += sel(i3, bcc, 0.0f) + sel(prv == 3, ab1, 0.0f) + sel(cc2 == 3, ab2, 0.0f);

            stg[(sess * 4 + tl) * 33 + k] = make_float4(l0, l1, l2, l3);
        }

        __syncthreads();
        // flush: 64B full-line chunks; 4 iterations cover 16KB quarter
#pragma unroll
        for (int j = 0; j < 4; ++j) {
            const int s  = tid >> 5;              // session 0..7
            const int ee = j * 32 + (tid & 31);   // kk = ee>>2, tl = ee&3
            const int kk = ee >> 2;
            const int tl = ee & 3;
            const float4 val = stg[(s * 4 + tl) * 33 + kk];
            out4[(size_t)(b0 + s) * T_ + kk * CH + h * 4 + tl] = val;
        }
        __syncthreads();
    }
}

extern "C" void kernel_launch(void* const* d_in, const int* in_sizes, int n_in,
                              void* d_out, int out_size, void* d_ws, size_t ws_size,
                              hipStream_t stream) {
    const float* inputs = (const float*)d_in[0];   // [8192, 512, 8] f32
    const float* params = (const float*)d_in[1];   // [13] f32
    float* out = (float*)d_out;                    // [8192, 512, 4] f32

    castro_one<<<dim3(B_ / 8), dim3(256), 0, stream>>>(inputs, params, out);
}

// Round 20
// 73.490 us; speedup vs baseline: 1.4625x; 1.4625x over previous
//
#include <hip/hip_runtime.h>
#include <math.h>

constexpr int B_ = 8192;
constexpr int T_ = 512;
constexpr int CH = 16;                     // steps per chunk
constexpr int NCH = T_ / CH;               // 32 chunks

__device__ __forceinline__ float sp_(float x) {
    return fmaxf(x, 0.0f) + log1pf(expf(-fabsf(x)));  // stable softplus
}
__device__ __forceinline__ float sg_(float x) { return 1.0f / (1.0f + expf(-x)); }
__device__ __forceinline__ float clipf(float x, float lo, float hi) { return fminf(fmaxf(x, lo), hi); }
__device__ __forceinline__ float sel(bool c, float a, float b) { return c ? a : b; }

// ONE kernel: raw input -> codes (LDS) -> affine maps + wave-scan -> logits -> staged flush.
// 16.9 KB LDS (8 blocks/CU) + launch_bounds(256,4) (VGPR 64, no spill — R18-proven).
__global__ __launch_bounds__(256, 4) void castro_one(const float* __restrict__ in,
                                                     const float* __restrict__ p,
                                                     float* __restrict__ out) {
    __shared__ char smem[8 * 4 * 33 * 16];   // 16896 B: codes (8KB) unioned with staging
    uint4* cc4 = reinterpret_cast<uint4*>(smem);          // [256]
    uint4* rr4 = reinterpret_cast<uint4*>(smem) + 256;    // [256]
    unsigned char* ccb = reinterpret_cast<unsigned char*>(cc4);
    unsigned char* rrb = reinterpret_cast<unsigned char*>(rr4);
    float4* stg = reinterpret_cast<float4*>(smem);        // [sess][tl][k(+1)] = [8][4][33]

    const int tid = threadIdx.x;
    const int b0  = blockIdx.x * 8;          // first session of this block

    // ---- phase 1: coalesced read of 8 sessions, bit-extract to LDS ----
    const float4* __restrict__ in4 = reinterpret_cast<const float4*>(in) + (size_t)b0 * 1024;
#pragma unroll
    for (int it = 0; it < 32; ++it) {
        const int idx  = it * 256 + tid;      // 0..8191, lane-contiguous
        const float4 fv = in4[idx];
        const int sess = idx >> 10;           // session within block
        const int step = (idx & 1023) >> 1;   // 2 float4 per step
        if ((idx & 1) == 0) {
            ccb[sess * 512 + step] =
                (unsigned char)(fv.y > 0.5f ? 1 : (fv.z > 0.5f ? 2 : (fv.w > 0.5f ? 3 : 0)));
        } else {
            rrb[sess * 512 + step] = (fv.x > 0.5f) ? 4 : 0;   // rewards broadcast: .x suffices
        }
    }
    __syncthreads();

    // ---- phase 2: per-(sess,chunk) map + width-32 shuffle scan (verbatim) ----
    const int w    = tid >> 6;
    const int lane = tid & 63;
    const int k    = lane & 31;                  // chunk index
    const int sess = w * 2 + (lane >> 5);        // session within block
    const int b    = b0 + sess;

    const float beta_r = clipf(sp_(p[0]), 0.01f, 20.0f);
    const float lapse  = clipf(sg_(p[1]), 0.01f, 0.99f);
    const float prior  = clipf(sp_(p[2]), 0.01f, 0.99f);
    const float alpha  = clipf(sg_(p[3]), 0.01f, 0.99f);
    const float decay  = clipf(sg_(p[4]), 0.01f, 0.99f);
    const float ab1    = p[5];
    const float ab2    = p[6];
    const float pers   = sp_(p[7]);
    const float sw     = p[8];
    const float gamma  = sp_(p[10]);
    const float temp   = clipf(sp_(p[11]) + 1e-6f, 1e-6f, 100.0f);
    const float beta_p = sp_(p[12]);
    const float brt = beta_r / temp;
    const float l4  = lapse * 0.25f;
    const float oml = 1.0f - lapse;

    const float e0k = alpha * __powf(1.0f - 1e-3f, (float)(CH * k));

    uint4 cw;
    {
        const uint4 c4 = cc4[sess * 32 + k];
        const uint4 r4 = rr4[sess * 32 + k];
        cw.x = c4.x | r4.x; cw.y = c4.y | r4.y; cw.z = c4.z | r4.z; cw.w = c4.w | r4.w;
    }
    __syncthreads();   // codes LDS dead; staging may overwrite

    float m[4][4], v[4], n[4];
#pragma unroll
    for (int i = 0; i < 4; ++i) {
#pragma unroll
        for (int j = 0; j < 4; ++j) m[i][j] = (i == j) ? 1.0f : 0.0f;
        v[i] = 0.0f; n[i] = 0.0f;
    }
    int prev = -1, run = 0;
    float e = e0k;

#pragma unroll
    for (int ti = 0; ti < CH; ++ti) {
        const unsigned word = (ti < 4) ? cw.x : (ti < 8) ? cw.y : (ti < 12) ? cw.z : cw.w;
        const unsigned byte = (word >> (8 * (ti & 3))) & 0xffu;
        const int  cc = (int)(byte & 3u);
        const bool rf = (byte & 4u) != 0u;
        const float tgt = rf ? 1.0f : -gamma;
        e *= (1.0f - 1e-3f);
        run = (cc == prev) ? (run + 1) : 1;
        prev = cc;
#pragma unroll
        for (int i = 0; i < 4; ++i) {
            const bool hit = (i == cc);
            v[i] = hit ? tgt : v[i];
            n[i] += hit ? 1.0f : 0.0f;
#pragma unroll
            for (int j = 0; j < 4; ++j) m[i][j] = hit ? 0.0f : m[i][j];
        }
        const float aa = decay * (1.0f - e);
        const float bf = decay * e * 0.25f;
        float csum[4];
#pragma unroll
        for (int j = 0; j < 4; ++j) csum[j] = bf * ((m[0][j] + m[1][j]) + (m[2][j] + m[3][j]));
        const float vs = bf * ((v[0] + v[1]) + (v[2] + v[3]));
#pragma unroll
        for (int i = 0; i < 4; ++i) {
#pragma unroll
            for (int j = 0; j < 4; ++j) m[i][j] = fmaf(aa, m[i][j], csum[j]);
            v[i] = fmaf(aa, v[i], vs);
        }
    }

    // inclusive shuffle-scan of (M,v) over k
    float sm[4][4], sv[4];
#pragma unroll
    for (int i = 0; i < 4; ++i) {
#pragma unroll
        for (int j = 0; j < 4; ++j) sm[i][j] = m[i][j];
        sv[i] = v[i];
    }
#pragma unroll
    for (int d = 1; d < 32; d <<= 1) {
        float pm[4][4], pv[4];
#pragma unroll
        for (int i = 0; i < 4; ++i) {
#pragma unroll
            for (int j = 0; j < 4; ++j) pm[i][j] = __shfl_up(sm[i][j], d, 32);
            pv[i] = __shfl_up(sv[i], d, 32);
        }
        if (k >= d) {
            float nm[4][4], nv[4];
#pragma unroll
            for (int i = 0; i < 4; ++i) {
#pragma unroll
                for (int j = 0; j < 4; ++j)
                    nm[i][j] = fmaf(sm[i][0], pm[0][j], fmaf(sm[i][1], pm[1][j],
                               fmaf(sm[i][2], pm[2][j], sm[i][3] * pm[3][j])));
                nv[i] = fmaf(sm[i][0], pv[0], fmaf(sm[i][1], pv[1],
                        fmaf(sm[i][2], pv[2], fmaf(sm[i][3], pv[3], sv[i]))));
            }
#pragma unroll
            for (int i = 0; i < 4; ++i) {
#pragma unroll
                for (int j = 0; j < 4; ++j) sm[i][j] = nm[i][j];
                sv[i] = nv[i];
            }
        }
    }

    // exclusive map -> starting q for chunk k
    float q[4];
#pragma unroll
    for (int i = 0; i < 4; ++i) {
        float er0 = __shfl_up(sm[i][0], 1, 32);
        float er1 = __shfl_up(sm[i][1], 1, 32);
        float er2 = __shfl_up(sm[i][2], 1, 32);
        float er3 = __shfl_up(sm[i][3], 1, 32);
        float ev  = __shfl_up(sv[i], 1, 32);
        if (k == 0) { er0 = (i == 0); er1 = (i == 1); er2 = (i == 2); er3 = (i == 3); ev = 0.0f; }
        q[i] = fmaf(prior, ((er0 + er1) + (er2 + er3)), ev);
    }

    // cum counts: exclusive prefix sum (bit-exact)
    float cex[4];
#pragma unroll
    for (int i = 0; i < 4; ++i) {
        float s = n[i];
#pragma unroll
        for (int d = 1; d < 32; d <<= 1) {
            const float t = __shfl_up(s, d, 32);
            if (k >= d) s += t;
        }
        cex[i] = s - n[i];
    }

    // tsls via trailing-run scan (bit-exact)
    const float lcf  = (float)prev;
    const float runf = (float)run;
    float lcm1 = __shfl_up(lcf, 1, 32);
    if (k == 0) lcm1 = -1.0f;
    const bool u = (runf == 16.0f) && (lcf == lcm1);
    const unsigned long long bal = __ballot(u);
    const unsigned gm = (unsigned)(bal >> (lane & 32));
    const unsigned vsh = (k == 31) ? gm : (gm << (31 - k));
    const int c = __clz(~vsh);
    const float runsrc = __shfl(runf, (lane & 32) + (k - c));
    const float TR = 16.0f * (float)c + runsrc;
    float TRm1 = __shfl_up(TR, 1, 32);
    const float tslsS = (k == 0) ? 0.0f : (TRm1 - 1.0f);
    const float lcprev = (k == 0) ? -1.0f : lcm1;

    // ---- phase 3: logits staged through LDS in FOUR quarters ----
    float q0 = q[0], q1 = q[1], q2 = q[2], q3 = q[3];
    float c0 = cex[0], c1 = cex[1], c2 = cex[2], c3 = cex[3];
    float tsls = tslsS;
    float expl = e0k;
    int oldc = (int)lcprev;

    float4* __restrict__ out4 = reinterpret_cast<float4*>(out);

#pragma unroll
    for (int h = 0; h < 4; ++h) {
#pragma unroll
        for (int tl = 0; tl < 4; ++tl) {
            const int ti = h * 4 + tl;
            const unsigned word = (ti < 4) ? cw.x : (ti < 8) ? cw.y : (ti < 12) ? cw.z : cw.w;
            const unsigned byte = (word >> (8 * (ti & 3))) & 0xffu;
            const int  cc = (int)(byte & 3u);
            const bool rf = (byte & 4u) != 0u;
            const float target = sel(rf, 1.0f, -gamma);
            const int prv = oldc;
            const bool same = (cc == oldc);
            tsls = sel(same, tsls + 1.0f, 0.0f);
            expl *= (1.0f - 1e-3f);
            const bool i0 = (cc == 0), i1 = (cc == 1), i2 = (cc == 2), i3 = (cc == 3);
            q0 = sel(i0, target, q0);  c0 += sel(i0, 1.0f, 0.0f);
            q1 = sel(i1, target, q1);  c1 += sel(i1, 1.0f, 0.0f);
            q2 = sel(i2, target, q2);  c2 += sel(i2, 1.0f, 0.0f);
            q3 = sel(i3, target, q3);  c3 += sel(i3, 1.0f, 0.0f);
            const float qm  = 0.25f * ((q0 + q1) + (q2 + q3));
            const float omd = (1.0f - expl) * decay;
            const float eqd = (expl * decay) * qm;
            q0 = fmaf(omd, q0, eqd);
            q1 = fmaf(omd, q1, eqd);
            q2 = fmaf(omd, q2, eqd);
            q3 = fmaf(omd, q3, eqd);
            oldc = cc;

            const float s0 = fmaf(brt, q0, beta_p * __logf(1.0f + c0));
            const float s1 = fmaf(brt, q1, beta_p * __logf(1.0f + c1));
            const float s2 = fmaf(brt, q2, beta_p * __logf(1.0f + c2));
            const float s3 = fmaf(brt, q3, beta_p * __logf(1.0f + c3));
            const float mx = fmaxf(fmaxf(s0, s1), fmaxf(s2, s3));
            const float e0 = __expf(s0 - mx);
            const float e1 = __expf(s1 - mx);
            const float e2 = __expf(s2 - mx);
            const float e3 = __expf(s3 - mx);
            const float iz = oml / ((e0 + e1) + (e2 + e3));

            float l0 = __logf(fmaf(e0, iz, l4));
            float l1 = __logf(fmaf(e1, iz, l4));
            float l2 = __logf(fmaf(e2, iz, l4));
            float l3 = __logf(fmaf(e3, iz, l4));

            const float bcc = sel(same, pers, sw) + __logf(tsls + 1.0f);
            const int cc2 = cc ^ 2;
            l0 += sel(i0, bcc, 0.0f) + sel(prv == 0, ab1, 0.0f) + sel(cc2 == 0, ab2, 0.0f);
            l1 += sel(i1, bcc, 0.0f) + sel(prv == 1, ab1, 0.0f) + sel(cc2 == 1, ab2, 0.0f);
            l2 += sel(i2, bcc, 0.0f) + sel(prv == 2, ab1, 0.0f) + sel(cc2 == 2, ab2, 0.0f);
            l3 += sel(i3, bcc, 0.0f) + sel(prv == 3, ab1, 0.0f) + sel(cc2 == 3, ab2, 0.0f);

            stg[(sess * 4 + tl) * 33 + k] = make_float4(l0, l1, l2, l3);
        }

        __syncthreads();
        // flush: 64B full-line chunks; 4 iterations cover the 16KB quarter
#pragma unroll
        for (int j = 0; j < 4; ++j) {
            const int s  = tid >> 5;              // session 0..7
            const int ee = j * 32 + (tid & 31);   // kk = ee>>2, tl = ee&3
            const int kk = ee >> 2;
            const int tl = ee & 3;
            const float4 val = stg[(s * 4 + tl) * 33 + kk];
            out4[(size_t)(b0 + s) * T_ + kk * CH + h * 4 + tl] = val;
        }
        __syncthreads();
    }
}

extern "C" void kernel_launch(void* const* d_in, const int* in_sizes, int n_in,
                              void* d_out, int out_size, void* d_ws, size_t ws_size,
                              hipStream_t stream) {
    const float* inputs = (const float*)d_in[0];   // [8192, 512, 8] f32
    const float* params = (const float*)d_in[1];   // [13] f32
    float* out = (float*)d_out;                    // [8192, 512, 4] f32

    castro_one<<<dim3(B_ / 8), dim3(256), 0, stream>>>(inputs, params, out);
}

// Round 21
// 71.919 us; speedup vs baseline: 1.4944x; 1.0218x over previous
//
#include <hip/hip_runtime.h>
#include <math.h>

constexpr int B_ = 8192;
constexpr int T_ = 512;
constexpr int CH = 8;                      // steps per chunk
constexpr int NCH = T_ / CH;               // 64 chunks = one full wave per session

__device__ __forceinline__ float sp_(float x) {
    return fmaxf(x, 0.0f) + log1pf(expf(-fabsf(x)));  // stable softplus
}
__device__ __forceinline__ float sg_(float x) { return 1.0f / (1.0f + expf(-x)); }
__device__ __forceinline__ float clipf(float x, float lo, float hi) { return fminf(fmaxf(x, lo), hi); }
__device__ __forceinline__ float sel(bool c, float a, float b) { return c ? a : b; }

// ONE kernel, CH=8: raw input -> codes (LDS) -> 8-step affine maps -> width-64 wave scan
// -> logits -> LDS-staged full-line flush. Block = 4 sessions (1 wave each), grid = 2048.
__global__ __launch_bounds__(256, 4) void castro_one(const float* __restrict__ in,
                                                     const float* __restrict__ p,
                                                     float* __restrict__ out) {
    __shared__ char smem[4 * 4 * 65 * 16];   // 16640 B: codes (4KB) unioned with staging
    uint2* cc2 = reinterpret_cast<uint2*>(smem);          // [4*64]
    uint2* rr2 = reinterpret_cast<uint2*>(smem) + 256;    // [4*64]
    unsigned char* ccb = reinterpret_cast<unsigned char*>(cc2);
    unsigned char* rrb = reinterpret_cast<unsigned char*>(rr2);
    float4* stg = reinterpret_cast<float4*>(smem);        // [sess][tl][k(+1)] = [4][4][65]

    const int tid = threadIdx.x;
    const int b0  = blockIdx.x * 4;          // first session of this block

    // ---- phase 1: coalesced read of 4 sessions (4096 float4), bit-extract to LDS ----
    const float4* __restrict__ in4 = reinterpret_cast<const float4*>(in) + (size_t)b0 * 1024;
#pragma unroll
    for (int it = 0; it < 16; ++it) {
        const int idx  = it * 256 + tid;      // 0..4095, lane-contiguous
        const float4 fv = in4[idx];
        const int sess = idx >> 10;           // session within block
        const int step = (idx & 1023) >> 1;   // 2 float4 per step
        if ((idx & 1) == 0) {
            ccb[sess * 512 + step] =
                (unsigned char)(fv.y > 0.5f ? 1 : (fv.z > 0.5f ? 2 : (fv.w > 0.5f ? 3 : 0)));
        } else {
            rrb[sess * 512 + step] = (fv.x > 0.5f) ? 4 : 0;   // rewards broadcast: .x suffices
        }
    }
    __syncthreads();

    // ---- phase 2: per-(sess,chunk) 8-step map + width-64 wave scan ----
    const int sess = tid >> 6;                   // wave = session
    const int k    = tid & 63;                   // chunk index 0..63
    const int b    = b0 + sess;

    const float beta_r = clipf(sp_(p[0]), 0.01f, 20.0f);
    const float lapse  = clipf(sg_(p[1]), 0.01f, 0.99f);
    const float prior  = clipf(sp_(p[2]), 0.01f, 0.99f);
    const float alpha  = clipf(sg_(p[3]), 0.01f, 0.99f);
    const float decay  = clipf(sg_(p[4]), 0.01f, 0.99f);
    const float ab1    = p[5];
    const float ab2    = p[6];
    const float pers   = sp_(p[7]);
    const float sw     = p[8];
    const float gamma  = sp_(p[10]);
    const float temp   = clipf(sp_(p[11]) + 1e-6f, 1e-6f, 100.0f);
    const float beta_p = sp_(p[12]);
    const float brt = beta_r / temp;
    const float l4  = lapse * 0.25f;
    const float oml = 1.0f - lapse;

    const float e0k = alpha * __powf(1.0f - 1e-3f, (float)(CH * k));

    uint2 cw;
    {
        const uint2 c2 = cc2[sess * 64 + k];
        const uint2 r2 = rr2[sess * 64 + k];
        cw.x = c2.x | r2.x; cw.y = c2.y | r2.y;
    }
    __syncthreads();   // codes LDS dead; staging may overwrite

    float m[4][4], v[4], n[4];
#pragma unroll
    for (int i = 0; i < 4; ++i) {
#pragma unroll
        for (int j = 0; j < 4; ++j) m[i][j] = (i == j) ? 1.0f : 0.0f;
        v[i] = 0.0f; n[i] = 0.0f;
    }
    int prev = -1, run = 0;
    float e = e0k;

#pragma unroll
    for (int ti = 0; ti < CH; ++ti) {
        const unsigned word = (ti < 4) ? cw.x : cw.y;
        const unsigned byte = (word >> (8 * (ti & 3))) & 0xffu;
        const int  cc = (int)(byte & 3u);
        const bool rf = (byte & 4u) != 0u;
        const float tgt = rf ? 1.0f : -gamma;
        e *= (1.0f - 1e-3f);
        run = (cc == prev) ? (run + 1) : 1;
        prev = cc;
#pragma unroll
        for (int i = 0; i < 4; ++i) {
            const bool hit = (i == cc);
            v[i] = hit ? tgt : v[i];
            n[i] += hit ? 1.0f : 0.0f;
#pragma unroll
            for (int j = 0; j < 4; ++j) m[i][j] = hit ? 0.0f : m[i][j];
        }
        const float aa = decay * (1.0f - e);
        const float bf = decay * e * 0.25f;
        float csum[4];
#pragma unroll
        for (int j = 0; j < 4; ++j) csum[j] = bf * ((m[0][j] + m[1][j]) + (m[2][j] + m[3][j]));
        const float vs = bf * ((v[0] + v[1]) + (v[2] + v[3]));
#pragma unroll
        for (int i = 0; i < 4; ++i) {
#pragma unroll
            for (int j = 0; j < 4; ++j) m[i][j] = fmaf(aa, m[i][j], csum[j]);
            v[i] = fmaf(aa, v[i], vs);
        }
    }

    // inclusive width-64 shuffle-scan of (M,v) over k (compose: cur ∘ prev)
    float sm[4][4], sv[4];
#pragma unroll
    for (int i = 0; i < 4; ++i) {
#pragma unroll
        for (int j = 0; j < 4; ++j) sm[i][j] = m[i][j];
        sv[i] = v[i];
    }
#pragma unroll
    for (int d = 1; d < 64; d <<= 1) {
        float pm[4][4], pv[4];
#pragma unroll
        for (int i = 0; i < 4; ++i) {
#pragma unroll
            for (int j = 0; j < 4; ++j) pm[i][j] = __shfl_up(sm[i][j], d, 64);
            pv[i] = __shfl_up(sv[i], d, 64);
        }
        if (k >= d) {
            float nm[4][4], nv[4];
#pragma unroll
            for (int i = 0; i < 4; ++i) {
#pragma unroll
                for (int j = 0; j < 4; ++j)
                    nm[i][j] = fmaf(sm[i][0], pm[0][j], fmaf(sm[i][1], pm[1][j],
                               fmaf(sm[i][2], pm[2][j], sm[i][3] * pm[3][j])));
                nv[i] = fmaf(sm[i][0], pv[0], fmaf(sm[i][1], pv[1],
                        fmaf(sm[i][2], pv[2], fmaf(sm[i][3], pv[3], sv[i]))));
            }
#pragma unroll
            for (int i = 0; i < 4; ++i) {
#pragma unroll
                for (int j = 0; j < 4; ++j) sm[i][j] = nm[i][j];
                sv[i] = nv[i];
            }
        }
    }

    // exclusive map -> starting q for chunk k
    float q[4];
#pragma unroll
    for (int i = 0; i < 4; ++i) {
        float er0 = __shfl_up(sm[i][0], 1, 64);
        float er1 = __shfl_up(sm[i][1], 1, 64);
        float er2 = __shfl_up(sm[i][2], 1, 64);
        float er3 = __shfl_up(sm[i][3], 1, 64);
        float ev  = __shfl_up(sv[i], 1, 64);
        if (k == 0) { er0 = (i == 0); er1 = (i == 1); er2 = (i == 2); er3 = (i == 3); ev = 0.0f; }
        q[i] = fmaf(prior, ((er0 + er1) + (er2 + er3)), ev);
    }

    // cum counts: exclusive prefix sum (bit-exact)
    float cex[4];
#pragma unroll
    for (int i = 0; i < 4; ++i) {
        float s = n[i];
#pragma unroll
        for (int d = 1; d < 64; d <<= 1) {
            const float t = __shfl_up(s, d, 64);
            if (k >= d) s += t;
        }
        cex[i] = s - n[i];
    }

    // tsls via trailing-run scan (bit-exact); full 64-bit ballot (wave = one session)
    const float lcf  = (float)prev;
    const float runf = (float)run;
    float lcm1 = __shfl_up(lcf, 1, 64);
    if (k == 0) lcm1 = -1.0f;
    const bool u = (runf == 8.0f) && (lcf == lcm1);
    const unsigned long long bal = __ballot(u);
    const unsigned long long vsh = (k == 63) ? bal : (bal << (63 - k));
    const int c = __clzll(~vsh);               // trailing consecutive u's ending at k
    const float runsrc = __shfl(runf, k - c, 64);
    const float TR = 8.0f * (float)c + runsrc; // trailing run at end of chunk k
    float TRm1 = __shfl_up(TR, 1, 64);
    const float tslsS = (k == 0) ? 0.0f : (TRm1 - 1.0f);
    const float lcprev = (k == 0) ? -1.0f : lcm1;

    // ---- phase 3: logits staged through LDS in two 4-step halves ----
    float q0 = q[0], q1 = q[1], q2 = q[2], q3 = q[3];
    float c0 = cex[0], c1 = cex[1], c2 = cex[2], c3 = cex[3];
    float tsls = tslsS;
    float expl = e0k;
    int oldc = (int)lcprev;

    float4* __restrict__ out4 = reinterpret_cast<float4*>(out);

#pragma unroll
    for (int h = 0; h < 2; ++h) {
#pragma unroll
        for (int tl = 0; tl < 4; ++tl) {
            const int ti = h * 4 + tl;
            const unsigned word = (ti < 4) ? cw.x : cw.y;
            const unsigned byte = (word >> (8 * (ti & 3))) & 0xffu;
            const int  cc = (int)(byte & 3u);
            const bool rf = (byte & 4u) != 0u;
            const float target = sel(rf, 1.0f, -gamma);
            const int prv = oldc;
            const bool same = (cc == oldc);
            tsls = sel(same, tsls + 1.0f, 0.0f);
            expl *= (1.0f - 1e-3f);
            const bool i0 = (cc == 0), i1 = (cc == 1), i2 = (cc == 2), i3 = (cc == 3);
            q0 = sel(i0, target, q0);  c0 += sel(i0, 1.0f, 0.0f);
            q1 = sel(i1, target, q1);  c1 += sel(i1, 1.0f, 0.0f);
            q2 = sel(i2, target, q2);  c2 += sel(i2, 1.0f, 0.0f);
            q3 = sel(i3, target, q3);  c3 += sel(i3, 1.0f, 0.0f);
            const float qm  = 0.25f * ((q0 + q1) + (q2 + q3));
            const float omd = (1.0f - expl) * decay;
            const float eqd = (expl * decay) * qm;
            q0 = fmaf(omd, q0, eqd);
            q1 = fmaf(omd, q1, eqd);
            q2 = fmaf(omd, q2, eqd);
            q3 = fmaf(omd, q3, eqd);
            oldc = cc;

            const float s0 = fmaf(brt, q0, beta_p * __logf(1.0f + c0));
            const float s1 = fmaf(brt, q1, beta_p * __logf(1.0f + c1));
            const float s2 = fmaf(brt, q2, beta_p * __logf(1.0f + c2));
            const float s3 = fmaf(brt, q3, beta_p * __logf(1.0f + c3));
            const float mx = fmaxf(fmaxf(s0, s1), fmaxf(s2, s3));
            const float e0 = __expf(s0 - mx);
            const float e1 = __expf(s1 - mx);
            const float e2 = __expf(s2 - mx);
            const float e3 = __expf(s3 - mx);
            const float iz = oml / ((e0 + e1) + (e2 + e3));

            float l0 = __logf(fmaf(e0, iz, l4));
            float l1 = __logf(fmaf(e1, iz, l4));
            float l2 = __logf(fmaf(e2, iz, l4));
            float l3 = __logf(fmaf(e3, iz, l4));

            const float bcc = sel(same, pers, sw) + __logf(tsls + 1.0f);
            const int cc2 = cc ^ 2;
            l0 += sel(i0, bcc, 0.0f) + sel(prv == 0, ab1, 0.0f) + sel(cc2 == 0, ab2, 0.0f);
            l1 += sel(i1, bcc, 0.0f) + sel(prv == 1, ab1, 0.0f) + sel(cc2 == 1, ab2, 0.0f);
            l2 += sel(i2, bcc, 0.0f) + sel(prv == 2, ab1, 0.0f) + sel(cc2 == 2, ab2, 0.0f);
            l3 += sel(i3, bcc, 0.0f) + sel(prv == 3, ab1, 0.0f) + sel(cc2 == 3, ab2, 0.0f);

            stg[(sess * 4 + tl) * 65 + k] = make_float4(l0, l1, l2, l3);
        }

        __syncthreads();
        // flush: 4 consecutive float4 (tl) per (s,kk) = full 64B lines; 4 iters x 256 thr
#pragma unroll
        for (int j = 0; j < 4; ++j) {
            const int s   = tid >> 6;             // session 0..3
            const int ee  = j * 64 + (tid & 63);  // kk = ee>>2, tl = ee&3
            const int kk  = ee >> 2;
            const int tl  = ee & 3;
            const float4 val = stg[(s * 4 + tl) * 65 + kk];
            out4[(size_t)(b0 + s) * T_ + kk * CH + h * 4 + tl] = val;
        }
        __syncthreads();
    }
}

extern "C" void kernel_launch(void* const* d_in, const int* in_sizes, int n_in,
                              void* d_out, int out_size, void* d_ws, size_t ws_size,
                              hipStream_t stream) {
    const float* inputs = (const float*)d_in[0];   // [8192, 512, 8] f32
    const float* params = (const float*)d_in[1];   // [13] f32
    float* out = (float*)d_out;                    // [8192, 512, 4] f32

    castro_one<<<dim3(B_ / 4), dim3(256), 0, stream>>>(inputs, params, out);
}

// Round 22
// 71.567 us; speedup vs baseline: 1.5018x; 1.0049x over previous
//
#include <hip/hip_runtime.h>
#include <math.h>

constexpr int B_ = 8192;
constexpr int T_ = 512;
constexpr int CH = 8;                      // steps per chunk
constexpr int NCH = T_ / CH;               // 64 chunks = one full wave per session

__device__ __forceinline__ float sp_(float x) {
    return fmaxf(x, 0.0f) + log1pf(expf(-fabsf(x)));  // stable softplus
}
__device__ __forceinline__ float sg_(float x) { return 1.0f / (1.0f + expf(-x)); }
__device__ __forceinline__ float clipf(float x, float lo, float hi) { return fminf(fmaxf(x, lo), hi); }
__device__ __forceinline__ float sel(bool c, float a, float b) { return c ? a : b; }

// ONE kernel, CH=8: codes (LDS) -> 8-step affine maps -> width-64 wave scan -> logits
// (integer-log LDS tables) -> LDS-staged full-line flush.
__global__ __launch_bounds__(256, 4) void castro_one(const float* __restrict__ in,
                                                     const float* __restrict__ p,
                                                     float* __restrict__ out) {
    __shared__ char smem[4 * 4 * 65 * 16];   // 16640 B: codes (4KB) unioned with staging
    __shared__ float tbl[513];               // log(1+i)
    __shared__ float tblb[513];              // beta_p * log(1+i)
    uint2* cc2 = reinterpret_cast<uint2*>(smem);          // [4*64]
    uint2* rr2 = reinterpret_cast<uint2*>(smem) + 256;    // [4*64]
    unsigned char* ccb = reinterpret_cast<unsigned char*>(cc2);
    unsigned char* rrb = reinterpret_cast<unsigned char*>(rr2);
    float4* stg = reinterpret_cast<float4*>(smem);        // [sess][tl][k(+1)] = [4][4][65]

    const int tid = threadIdx.x;
    const int b0  = blockIdx.x * 4;          // first session of this block

    const float beta_p = sp_(p[12]);

    // build log tables (bit-identical to the __logf calls they replace)
    for (int i = tid; i < 513; i += 256) {
        const float lg = __logf(1.0f + (float)i);
        tbl[i]  = lg;
        tblb[i] = beta_p * lg;
    }

    // ---- phase 1: coalesced read of 4 sessions (4096 float4), bit-extract to LDS ----
    const float4* __restrict__ in4 = reinterpret_cast<const float4*>(in) + (size_t)b0 * 1024;
#pragma unroll
    for (int it = 0; it < 16; ++it) {
        const int idx  = it * 256 + tid;      // 0..4095, lane-contiguous
        const float4 fv = in4[idx];
        const int sess = idx >> 10;           // session within block
        const int step = (idx & 1023) >> 1;   // 2 float4 per step
        if ((idx & 1) == 0) {
            ccb[sess * 512 + step] =
                (unsigned char)(fv.y > 0.5f ? 1 : (fv.z > 0.5f ? 2 : (fv.w > 0.5f ? 3 : 0)));
        } else {
            rrb[sess * 512 + step] = (fv.x > 0.5f) ? 4 : 0;   // rewards broadcast: .x suffices
        }
    }
    __syncthreads();

    // ---- phase 2: per-(sess,chunk) 8-step map + width-64 wave scan ----
    const int sess = tid >> 6;                   // wave = session
    const int k    = tid & 63;                   // chunk index 0..63
    const int b    = b0 + sess;

    const float beta_r = clipf(sp_(p[0]), 0.01f, 20.0f);
    const float lapse  = clipf(sg_(p[1]), 0.01f, 0.99f);
    const float prior  = clipf(sp_(p[2]), 0.01f, 0.99f);
    const float alpha  = clipf(sg_(p[3]), 0.01f, 0.99f);
    const float decay  = clipf(sg_(p[4]), 0.01f, 0.99f);
    const float ab1    = p[5];
    const float ab2    = p[6];
    const float pers   = sp_(p[7]);
    const float sw     = p[8];
    const float gamma  = sp_(p[10]);
    const float temp   = clipf(sp_(p[11]) + 1e-6f, 1e-6f, 100.0f);
    const float brt = beta_r / temp;
    const float l4  = lapse * 0.25f;
    const float oml = 1.0f - lapse;

    const float e0k = alpha * __powf(1.0f - 1e-3f, (float)(CH * k));

    uint2 cw;
    {
        const uint2 c2 = cc2[sess * 64 + k];
        const uint2 r2 = rr2[sess * 64 + k];
        cw.x = c2.x | r2.x; cw.y = c2.y | r2.y;
    }
    __syncthreads();   // codes LDS dead; staging may overwrite

    float m[4][4], v[4], n[4];
#pragma unroll
    for (int i = 0; i < 4; ++i) {
#pragma unroll
        for (int j = 0; j < 4; ++j) m[i][j] = (i == j) ? 1.0f : 0.0f;
        v[i] = 0.0f; n[i] = 0.0f;
    }
    int prev = -1, run = 0;
    float e = e0k;

#pragma unroll
    for (int ti = 0; ti < CH; ++ti) {
        const unsigned word = (ti < 4) ? cw.x : cw.y;
        const unsigned byte = (word >> (8 * (ti & 3))) & 0xffu;
        const int  cc = (int)(byte & 3u);
        const bool rf = (byte & 4u) != 0u;
        const float tgt = rf ? 1.0f : -gamma;
        e *= (1.0f - 1e-3f);
        run = (cc == prev) ? (run + 1) : 1;
        prev = cc;
#pragma unroll
        for (int i = 0; i < 4; ++i) {
            const bool hit = (i == cc);
            v[i] = hit ? tgt : v[i];
            n[i] += hit ? 1.0f : 0.0f;
#pragma unroll
            for (int j = 0; j < 4; ++j) m[i][j] = hit ? 0.0f : m[i][j];
        }
        const float aa = decay * (1.0f - e);
        const float bf = decay * e * 0.25f;
        float csum[4];
#pragma unroll
        for (int j = 0; j < 4; ++j) csum[j] = bf * ((m[0][j] + m[1][j]) + (m[2][j] + m[3][j]));
        const float vs = bf * ((v[0] + v[1]) + (v[2] + v[3]));
#pragma unroll
        for (int i = 0; i < 4; ++i) {
#pragma unroll
            for (int j = 0; j < 4; ++j) m[i][j] = fmaf(aa, m[i][j], csum[j]);
            v[i] = fmaf(aa, v[i], vs);
        }
    }

    // inclusive width-64 shuffle-scan of (M,v) over k (compose: cur ∘ prev)
    float sm[4][4], sv[4];
#pragma unroll
    for (int i = 0; i < 4; ++i) {
#pragma unroll
        for (int j = 0; j < 4; ++j) sm[i][j] = m[i][j];
        sv[i] = v[i];
    }
#pragma unroll
    for (int d = 1; d < 64; d <<= 1) {
        float pm[4][4], pv[4];
#pragma unroll
        for (int i = 0; i < 4; ++i) {
#pragma unroll
            for (int j = 0; j < 4; ++j) pm[i][j] = __shfl_up(sm[i][j], d, 64);
            pv[i] = __shfl_up(sv[i], d, 64);
        }
        if (k >= d) {
            float nm[4][4], nv[4];
#pragma unroll
            for (int i = 0; i < 4; ++i) {
#pragma unroll
                for (int j = 0; j < 4; ++j)
                    nm[i][j] = fmaf(sm[i][0], pm[0][j], fmaf(sm[i][1], pm[1][j],
                               fmaf(sm[i][2], pm[2][j], sm[i][3] * pm[3][j])));
                nv[i] = fmaf(sm[i][0], pv[0], fmaf(sm[i][1], pv[1],
                        fmaf(sm[i][2], pv[2], fmaf(sm[i][3], pv[3], sv[i]))));
            }
#pragma unroll
            for (int i = 0; i < 4; ++i) {
#pragma unroll
                for (int j = 0; j < 4; ++j) sm[i][j] = nm[i][j];
                sv[i] = nv[i];
            }
        }
    }

    // exclusive map -> starting q for chunk k
    float q[4];
#pragma unroll
    for (int i = 0; i < 4; ++i) {
        float er0 = __shfl_up(sm[i][0], 1, 64);
        float er1 = __shfl_up(sm[i][1], 1, 64);
        float er2 = __shfl_up(sm[i][2], 1, 64);
        float er3 = __shfl_up(sm[i][3], 1, 64);
        float ev  = __shfl_up(sv[i], 1, 64);
        if (k == 0) { er0 = (i == 0); er1 = (i == 1); er2 = (i == 2); er3 = (i == 3); ev = 0.0f; }
        q[i] = fmaf(prior, ((er0 + er1) + (er2 + er3)), ev);
    }

    // cum counts: exclusive prefix sum (bit-exact)
    float cex[4];
#pragma unroll
    for (int i = 0; i < 4; ++i) {
        float s = n[i];
#pragma unroll
        for (int d = 1; d < 64; d <<= 1) {
            const float t = __shfl_up(s, d, 64);
            if (k >= d) s += t;
        }
        cex[i] = s - n[i];
    }

    // tsls via trailing-run scan (bit-exact); full 64-bit ballot (wave = one session)
    const float lcf  = (float)prev;
    const float runf = (float)run;
    float lcm1 = __shfl_up(lcf, 1, 64);
    if (k == 0) lcm1 = -1.0f;
    const bool u = (runf == 8.0f) && (lcf == lcm1);
    const unsigned long long bal = __ballot(u);
    const unsigned long long vsh = (k == 63) ? bal : (bal << (63 - k));
    const int c = __clzll(~vsh);               // trailing consecutive u's ending at k
    const float runsrc = __shfl(runf, k - c, 64);
    const float TR = 8.0f * (float)c + runsrc; // trailing run at end of chunk k
    float TRm1 = __shfl_up(TR, 1, 64);
    const float tslsS = (k == 0) ? 0.0f : (TRm1 - 1.0f);
    const float lcprev = (k == 0) ? -1.0f : lcm1;

    // ---- phase 3: logits staged through LDS in two 4-step halves ----
    float q0 = q[0], q1 = q[1], q2 = q[2], q3 = q[3];
    float c0 = cex[0], c1 = cex[1], c2 = cex[2], c3 = cex[3];
    float tsls = tslsS;
    float expl = e0k;
    int oldc = (int)lcprev;

    float4* __restrict__ out4 = reinterpret_cast<float4*>(out);

#pragma unroll
    for (int h = 0; h < 2; ++h) {
#pragma unroll
        for (int tl = 0; tl < 4; ++tl) {
            const int ti = h * 4 + tl;
            const unsigned word = (ti < 4) ? cw.x : cw.y;
            const unsigned byte = (word >> (8 * (ti & 3))) & 0xffu;
            const int  cc = (int)(byte & 3u);
            const bool rf = (byte & 4u) != 0u;
            const float target = sel(rf, 1.0f, -gamma);
            const int prv = oldc;
            const bool same = (cc == oldc);
            tsls = sel(same, tsls + 1.0f, 0.0f);
            expl *= (1.0f - 1e-3f);
            const bool i0 = (cc == 0), i1 = (cc == 1), i2 = (cc == 2), i3 = (cc == 3);
            q0 = sel(i0, target, q0);  c0 += sel(i0, 1.0f, 0.0f);
            q1 = sel(i1, target, q1);  c1 += sel(i1, 1.0f, 0.0f);
            q2 = sel(i2, target, q2);  c2 += sel(i2, 1.0f, 0.0f);
            q3 = sel(i3, target, q3);  c3 += sel(i3, 1.0f, 0.0f);
            const float qm  = 0.25f * ((q0 + q1) + (q2 + q3));
            const float omd = (1.0f - expl) * decay;
            const float eqd = (expl * decay) * qm;
            q0 = fmaf(omd, q0, eqd);
            q1 = fmaf(omd, q1, eqd);
            q2 = fmaf(omd, q2, eqd);
            q3 = fmaf(omd, q3, eqd);
            oldc = cc;

            // integer-log table lookups (bit-identical to __logf(1+c))
            const float s0 = fmaf(brt, q0, tblb[(int)c0]);
            const float s1 = fmaf(brt, q1, tblb[(int)c1]);
            const float s2 = fmaf(brt, q2, tblb[(int)c2]);
            const float s3 = fmaf(brt, q3, tblb[(int)c3]);
            const float mx = fmaxf(fmaxf(s0, s1), fmaxf(s2, s3));
            const float e0 = __expf(s0 - mx);
            const float e1 = __expf(s1 - mx);
            const float e2 = __expf(s2 - mx);
            const float e3 = __expf(s3 - mx);
            const float iz = oml / ((e0 + e1) + (e2 + e3));

            float l0 = __logf(fmaf(e0, iz, l4));
            float l1 = __logf(fmaf(e1, iz, l4));
            float l2 = __logf(fmaf(e2, iz, l4));
            float l3 = __logf(fmaf(e3, iz, l4));

            const float bcc = sel(same, pers, sw) + tbl[(int)tsls];
            const int cc2 = cc ^ 2;
            l0 += sel(i0, bcc, 0.0f) + sel(prv == 0, ab1, 0.0f) + sel(cc2 == 0, ab2, 0.0f);
            l1 += sel(i1, bcc, 0.0f) + sel(prv == 1, ab1, 0.0f) + sel(cc2 == 1, ab2, 0.0f);
            l2 += sel(i2, bcc, 0.0f) + sel(prv == 2, ab1, 0.0f) + sel(cc2 == 2, ab2, 0.0f);
            l3 += sel(i3, bcc, 0.0f) + sel(prv == 3, ab1, 0.0f) + sel(cc2 == 3, ab2, 0.0f);

            stg[(sess * 4 + tl) * 65 + k] = make_float4(l0, l1, l2, l3);
        }

        __syncthreads();
        // flush: 4 consecutive float4 (tl) per (s,kk) = full 64B lines; 4 iters x 256 thr
#pragma unroll
        for (int j = 0; j < 4; ++j) {
            const int s   = tid >> 6;             // session 0..3
            const int ee  = j * 64 + (tid & 63);  // kk = ee>>2, tl = ee&3
            const int kk  = ee >> 2;
            const int tl  = ee & 3;
            const float4 val = stg[(s * 4 + tl) * 65 + kk];
            out4[(size_t)(b0 + s) * T_ + kk * CH + h * 4 + tl] = val;
        }
        __syncthreads();
    }
}

extern "C" void kernel_launch(void* const* d_in, const int* in_sizes, int n_in,
                              void* d_out, int out_size, void* d_ws, size_t ws_size,
                              hipStream_t stream) {
    const float* inputs = (const float*)d_in[0];   // [8192, 512, 8] f32
    const float* params = (const float*)d_in[1];   // [13] f32
    float* out = (float*)d_out;                    // [8192, 512, 4] f32

    castro_one<<<dim3(B_ / 4), dim3(256), 0, stream>>>(inputs, params, out);
}